// Round 8
// baseline (488.387 us; speedup 1.0000x reference)
//
#include <hip/hip_runtime.h>

// Problem constants (from reference): B=64, TOPK=2, E=16, C=1024, K=4096
#define BB    64
#define TOPK  2
#define EE    16
#define CC    1024
#define KK    4096

constexpr int RPB = 16;            // weight rows per tile (4 per wave)
constexpr int NCT = 2;             // row-tiles per block (double-depth burst)
constexpr int P   = 8;             // max (token,slot) pairs per pass
constexpr int KS  = 8;             // K-split (partials to workspace)
constexpr int KH  = KK / KS;       // floats per K-slice (=512)
constexpr int NW  = KH / 4 / 64;   // float4 windows per slice per lane (=2)

typedef float v4f __attribute__((ext_vector_type(4)));

// ---------------------------------------------------------------------------
// Kernel 1: grid = E * 32 * KS = 4096 one-shot blocks.
//
// Round-7 lesson: counted-vmcnt on the old structure was null (-1%) — the
// drain wasn't binding; the ~45% load duty cycle is structural (per block:
// ~800cy routing + ~3200cy load burst + ~1000cy dead compute tail, blocks
// convoying). Round-8 restructure doubles per-block load depth:
//   * NCT=2 row-tiles per block: 32 KB of weights issued as ONE 16-instr
//     burst before the staging wait. Tile-0 compute starts as soon as its
//     8 loads land (compiler incremental vmcnt); tile-1's 16 KB keeps
//     arriving UNDER tile-0's compute+butterfly+store. Dead tail shrinks
//     to tile-1's compute only.
//   * P=8 (LDS 16 KB, val[32]): frees VGPRs for the 2nd weight buffer;
//     w[2][NW][4] (64) + val[32] ~= 116 VGPR -> stays in 4-waves/SIMD band.
//   * 4096 blocks: half the routing preambles, half the act traffic.
// n>8 (~40% of blocks): extra passes reuse in-register weights, restage
// act only (full-drain barriers; nothing heavy left in flight).
// No atomics (butterfly finishes each sum in one lane -> plain store).
// ---------------------------------------------------------------------------
__global__ __launch_bounds__(256, 4) void moe_mlp2(
    const float* __restrict__ act, const int* __restrict__ idx,
    const float* __restrict__ W, float* __restrict__ partial)
{
    __shared__ float sact[P][KH];      // 8 x 512 x 4B = 16 KB
    __shared__ int   slist[BB * TOPK];
    __shared__ int   scnt;

    const int bid  = blockIdx.x;
    const int e    = bid >> 8;                // 256 blocks per expert
    const int ct2  = (bid >> 3) & 31;         // 32 tile-pairs
    const int ks   = bid & (KS - 1);          // 8 K-slices
    const int tid  = threadIdx.x;
    const int lane = tid & 63;
    const int wave = tid >> 6;
    const int row0 = ct2 * (RPB * NCT) + wave * 4;   // tile 0; tile 1 = +RPB

    // --- in-block routing: both barriers happen before any heavy load ---
    if (tid == 0) scnt = 0;
    __syncthreads();
    if (tid < BB * TOPK && idx[tid] == e) {
        int pos = atomicAdd(&scnt, 1);       // LDS atomic; order irrelevant
        slist[pos] = tid;                    // pair id = b*TOPK + slot
    }
    __syncthreads();
    const int n = scnt;
    if (n == 0) return;

    const v4f* __restrict__ Wb =
        (const v4f*)(W + (size_t)(e * CC + row0) * KK + ks * KH);

    // --- async global->LDS act staging for one pass. Half-row granularity:
    //     one wave-instr = 64 lanes x 16B = 1 KB = KH/2 floats. lds dest is
    //     wave-uniform base + lane*16 (HW rule); per-lane offset lives in
    //     the global src address. Per wave: <= 2*P/4 = 4 instrs. ---
    auto STAGE = [&](int g, int np) {
        for (int h = wave; h < 2 * np; h += 4) {
            int pr = slist[g + (h >> 1)];
            const float* gsrc = act + (size_t)pr * KK + ks * KH
                              + (h & 1) * (KH / 2) + lane * 4;
            __builtin_amdgcn_global_load_lds(
                (const __attribute__((address_space(1))) void*)gsrc,
                (__attribute__((address_space(3))) void*)
                    &sact[h >> 1][(h & 1) * (KH / 2)],
                16, 0, 0);
        }
    };

    // --- first pass: staging FIRST (oldest in vmcnt queue), then BOTH
    //     tiles' weights (16 nt dwordx4, kw-major within each tile), then
    //     counted wait. vmcnt(16) == "all but my 16 weight loads" == my
    //     staging is done (each wave issued <=4 staging + exactly 16 wt). ---
    v4f w[NCT][NW][4];   // issue order == use order
    {
        const int np0 = min(P, n);
        STAGE(0, np0);
        __builtin_amdgcn_sched_barrier(0);   // pin: staging before weights
#pragma unroll
        for (int t = 0; t < NCT; t++)
#pragma unroll
            for (int kw = 0; kw < NW; kw++)
#pragma unroll
                for (int r = 0; r < 4; r++)
                    w[t][kw][r] = __builtin_nontemporal_load(
                        Wb + ((size_t)t * RPB + r) * (KK / 4) + kw * 64 + lane);
        __builtin_amdgcn_sched_barrier(0);   // pin: weights before wait
        asm volatile("s_waitcnt vmcnt(16)" ::: "memory");
        __builtin_amdgcn_sched_barrier(0);
        __builtin_amdgcn_s_barrier();        // all waves' staging visible
        __builtin_amdgcn_sched_barrier(0);   // no ds_read hoisted above
    }

    // --- compute + butterfly + store for one tile from a register buffer ---
    auto TILE = [&](const v4f (&wt)[NW][4], int row, int g, int np) {
        // val[(p<<2)|r] = lane's partial for (pair p, row r); 32 slots
        float val[32];
#pragma unroll
        for (int i = 0; i < 32; i++) val[i] = 0.f;

#pragma unroll
        for (int kw = 0; kw < NW; kw++) {
            const int fb = (kw * 64 + lane) * 4;   // float idx within slice
#pragma unroll
            for (int pc = 0; pc < P / 4; pc++) {
                if (pc * 4 < np) {                  // wave-uniform guard
#pragma unroll
                    for (int j = 0; j < 4; j++) {
                        const int p = pc * 4 + j;
                        const v4f a = *(const v4f*)&sact[p][fb];
#pragma unroll
                        for (int r = 0; r < 4; r++)
                            val[(p << 2) | r] +=
                                wt[kw][r].x * a.x + wt[kw][r].y * a.y +
                                wt[kw][r].z * a.z + wt[kw][r].w * a.w;
                    }
                }
            }
        }

        // Butterfly: 5 value-halving steps within 32-lane halves (31 shfls)
        // + one cross-half add. Invariant: after step s, slot i
        // (i % 2^(s+1)==0) holds the 2^(s+1)-lane partial of logical value
        // (i | (lane & (2^(s+1)-1))). Lanes l and l+32 end with value l&31.
        // Dead pairs (>=np) are exact zeros.
#pragma unroll
        for (int s = 0; s < 5; s++) {
            const int m = 1 << s;
            const bool hi = (lane & m) != 0;
#pragma unroll
            for (int i = 0; i < 32; i += 2 * m) {
                float send = hi ? val[i] : val[i + m];
                float recv = __shfl_xor(send, m, 64);
                val[i] = (hi ? val[i + m] : val[i]) + recv;
            }
        }
        float v0 = val[0];
        v0 += __shfl_xor(v0, 32, 64);

        // lane l<32 owns (pair = (l&31)>>2, row = row + (l&3));
        // each (pair,ks,row) written exactly once -> plain store, no atomics
        const int p = (lane & 31) >> 2;
        if (lane < 32 && p < np) {
            int pr = slist[g + p];
            partial[((size_t)pr * KS + ks) * CC + row + (lane & 3)] = v0;
        }
    };

    for (int g = 0; g < n; g += P) {
        const int np = min(P, n - g);
        if (g) {   // n>8 path: weights already in regs; restage act only
            __syncthreads();
            STAGE(g, np);
            __syncthreads();
        }
        TILE(w[0], row0, g, np);
        TILE(w[1], row0 + RPB, g, np);
    }
}

// ---------------------------------------------------------------------------
// Kernel 2: finalize — out = resid + sum_s ew * (bias + sum_ks partial).
// 256 blocks; all reads fully coalesced; partial (4 MB) is L2/IF-hot.
// ---------------------------------------------------------------------------
__global__ __launch_bounds__(256) void finalize(
    const int* __restrict__ idx, const float* __restrict__ ew,
    const float* __restrict__ bias, const float* __restrict__ resid,
    const float* __restrict__ partial, float* __restrict__ out)
{
    const int i = blockIdx.x * 256 + threadIdx.x;   // [0, B*C)
    const int b = i >> 10;                           // C = 1024
    const int c = i & (CC - 1);
    float v = resid[i];
#pragma unroll
    for (int s = 0; s < TOPK; s++) {
        const int pr = b * TOPK + s;
        const int e  = idx[pr];
        float t = bias[e * CC + c];
#pragma unroll
        for (int ks = 0; ks < KS; ks++)
            t += partial[((size_t)pr * KS + ks) * CC + c];
        v += ew[pr] * t;
    }
    out[i] = v;
}

extern "C" void kernel_launch(void* const* d_in, const int* in_sizes, int n_in,
                              void* d_out, int out_size, void* d_ws, size_t ws_size,
                              hipStream_t stream) {
    const float* act   = (const float*)d_in[0];   // [B, TOPK, K]
    const int*   idx   = (const int*)d_in[1];     // [B, TOPK]
    const float* ew    = (const float*)d_in[2];   // [B, TOPK]
    const float* W     = (const float*)d_in[3];   // [E, C, K]
    const float* bias  = (const float*)d_in[4];   // [E, C]
    const float* resid = (const float*)d_in[5];   // [B, C]
    float* out = (float*)d_out;

    float* partial = (float*)d_ws;    // [B*TOPK][KS][C] = 4 MB

    moe_mlp2<<<EE * 32 * KS, 256, 0, stream>>>(act, idx, W, partial);
    finalize<<<(BB * CC) / 256, 256, 0, stream>>>(
        idx, ew, bias, resid, partial, out);
}

// Round 9
// 364.318 us; speedup vs baseline: 1.3406x; 1.3406x over previous
//
#include <hip/hip_runtime.h>

// Problem constants (from reference): B=64, TOPK=2, E=16, C=1024, K=4096
#define BB    64
#define TOPK  2
#define EE    16
#define CC    1024
#define KK    4096

constexpr int RPB = 16;            // weight rows per block (4 per wave)
constexpr int P   = 8;             // max (token,slot) pairs per pass
constexpr int KS  = 16;            // K-split (partials to workspace)
constexpr int KH  = KK / KS;       // floats per K-slice (=256)

typedef float v4f __attribute__((ext_vector_type(4)));

// ---------------------------------------------------------------------------
// Kernel 1: grid = E * 64 * KS = 16384 one-shot blocks, 256 threads.
//
// Round-8 post-mortem: NCT=2 needed ~130 VGPR; allocator pinned 64 and
// spilled the weight buffers to scratch (WRITE_SIZE 453 MB) -> 488us. But it
// also proved 4.05 TB/s HBM is reachable (r4: 87% occupancy, 3.2 TB/s even
// under atomic thrash). The binding constraint is resident waves, and every
// failed attempt died of SELF-INFLICTED traffic (r4 atomics, r8 spills).
//
// Round-9: high-occupancy small blocks with minimal traffic AND minimal
// register demand:
//   * KS=16: per-wave weights = 4 nt dwordx4 = 16 VGPR; val[32] = 32;
//     total ~70 VGPR. __launch_bounds__(256,6) caps at ~85 — no spill
//     cliff. Expect 6-7 waves/SIMD (~24-28 waves/CU, 1.6x r7).
//   * P=8, LDS 9 KB; partial-store epilogue (no atomics -> WRITE ~8 MB).
//   * No asm vmcnt/sched_barrier games (null in r7, spill risk in r8):
//     plain __syncthreads().
// Weights read exactly once (nt, held in regs); act staged from L2.
// ---------------------------------------------------------------------------
__global__ __launch_bounds__(256, 6) void moe_mlp2(
    const float* __restrict__ act, const int* __restrict__ idx,
    const float* __restrict__ W, float* __restrict__ partial)
{
    __shared__ float sact[P][KH];      // 8 x 256 x 4B = 8 KB
    __shared__ int   slist[BB * TOPK];
    __shared__ int   scnt;

    const int bid  = blockIdx.x;
    const int e    = bid >> 10;               // 1024 blocks per expert
    const int ct   = (bid >> 4) & 63;         // 64 row-tiles
    const int ks   = bid & (KS - 1);          // 16 K-slices
    const int tid  = threadIdx.x;
    const int lane = tid & 63;
    const int wave = tid >> 6;
    const int row0 = ct * RPB + wave * 4;

    // --- in-block routing: both barriers happen before any heavy load ---
    if (tid == 0) scnt = 0;
    __syncthreads();
    if (tid < BB * TOPK && idx[tid] == e) {
        int pos = atomicAdd(&scnt, 1);       // LDS atomic; order irrelevant
        slist[pos] = tid;                    // pair id = b*TOPK + slot
    }
    __syncthreads();
    const int n = scnt;
    if (n == 0) return;

    // --- weight slice prefetch: 4 nt dwordx4 per lane (1 KB per wave-row),
    //     issued back-to-back; drained by the first staging barrier ---
    const v4f* __restrict__ Wb =
        (const v4f*)(W + (size_t)(e * CC + row0) * KK + ks * KH);
    v4f w[4];
#pragma unroll
    for (int r = 0; r < 4; r++)
        w[r] = __builtin_nontemporal_load(Wb + (size_t)r * (KK / 4) + lane);

    for (int g = 0; g < n; g += P) {
        const int np = min(P, n - g);
        if (g) __syncthreads();   // prev pass's reads done before re-stage

        // --- async global->LDS staging: one instr per act row (64 lanes x
        //     16B = 1 KB = KH floats). lds dest is wave-uniform (HW rule);
        //     per-lane offset lives in the global src address. <=2 per wave.
        for (int h = wave; h < np; h += 4) {
            int pr = slist[g + h];
            const float* gsrc = act + (size_t)pr * KK + ks * KH + lane * 4;
            __builtin_amdgcn_global_load_lds(
                (const __attribute__((address_space(1))) void*)gsrc,
                (__attribute__((address_space(3))) void*)&sact[h][0],
                16, 0, 0);
        }
        __syncthreads();   // drains staging (and, first pass, the weights)

        // --- accumulate: val[(p<<2)|r] = lane's partial for (pair p, row r)
        float val[32];
#pragma unroll
        for (int i = 0; i < 32; i++) val[i] = 0.f;

        const int fb = lane * 4;   // this lane's 4 floats of the slice
#pragma unroll
        for (int pc = 0; pc < P / 4; pc++) {
            if (pc * 4 < np) {                  // wave-uniform guard
#pragma unroll
                for (int j = 0; j < 4; j++) {
                    const int p = pc * 4 + j;
                    const v4f a = *(const v4f*)&sact[p][fb];
#pragma unroll
                    for (int r = 0; r < 4; r++)
                        val[(p << 2) | r] += w[r].x * a.x + w[r].y * a.y +
                                             w[r].z * a.z + w[r].w * a.w;
                }
            }
        }

        // --- butterfly: 5 value-halving steps within 32-lane halves
        //     (31 shfls) + one cross-half add. Invariant: after step s,
        //     slot i (i % 2^(s+1)==0) holds the 2^(s+1)-lane partial of
        //     logical value (i | (lane & (2^(s+1)-1))). Lanes l and l+32
        //     both end with value l&31. Dead pairs (>=np) are exact zeros.
#pragma unroll
        for (int s = 0; s < 5; s++) {
            const int m = 1 << s;
            const bool hi = (lane & m) != 0;
#pragma unroll
            for (int i = 0; i < 32; i += 2 * m) {
                float send = hi ? val[i] : val[i + m];
                float recv = __shfl_xor(send, m, 64);
                val[i] = (hi ? val[i + m] : val[i]) + recv;
            }
        }
        float v0 = val[0];
        v0 += __shfl_xor(v0, 32, 64);

        // lane l<32 owns (pair = (l&31)>>2, row = row0 + (l&3)); each
        // (pair,ks,row) written exactly once -> plain store, no atomics
        const int p = (lane & 31) >> 2;
        if (lane < 32 && p < np) {
            int pr = slist[g + p];
            partial[((size_t)pr * KS + ks) * CC + row0 + (lane & 3)] = v0;
        }
    }
}

// ---------------------------------------------------------------------------
// Kernel 2: finalize — out = resid + sum_s ew * (bias + sum_ks partial).
// 256 blocks; all reads fully coalesced; partial (8 MB) is L2/IF-hot.
// ---------------------------------------------------------------------------
__global__ __launch_bounds__(256) void finalize(
    const int* __restrict__ idx, const float* __restrict__ ew,
    const float* __restrict__ bias, const float* __restrict__ resid,
    const float* __restrict__ partial, float* __restrict__ out)
{
    const int i = blockIdx.x * 256 + threadIdx.x;   // [0, B*C)
    const int b = i >> 10;                           // C = 1024
    const int c = i & (CC - 1);
    float v = resid[i];
#pragma unroll
    for (int s = 0; s < TOPK; s++) {
        const int pr = b * TOPK + s;
        const int e  = idx[pr];
        float t = bias[e * CC + c];
#pragma unroll
        for (int ks = 0; ks < KS; ks++)
            t += partial[((size_t)pr * KS + ks) * CC + c];
        v += ew[pr] * t;
    }
    out[i] = v;
}

extern "C" void kernel_launch(void* const* d_in, const int* in_sizes, int n_in,
                              void* d_out, int out_size, void* d_ws, size_t ws_size,
                              hipStream_t stream) {
    const float* act   = (const float*)d_in[0];   // [B, TOPK, K]
    const int*   idx   = (const int*)d_in[1];     // [B, TOPK]
    const float* ew    = (const float*)d_in[2];   // [B, TOPK]
    const float* W     = (const float*)d_in[3];   // [E, C, K]
    const float* bias  = (const float*)d_in[4];   // [E, C]
    const float* resid = (const float*)d_in[5];   // [B, C]
    float* out = (float*)d_out;

    float* partial = (float*)d_ws;    // [B*TOPK][KS][C] = 8 MB

    moe_mlp2<<<EE * 64 * KS, 256, 0, stream>>>(act, idx, W, partial);
    finalize<<<(BB * CC) / 256, 256, 0, stream>>>(
        idx, ew, bias, resid, partial, out);
}

// Round 10
// 359.960 us; speedup vs baseline: 1.3568x; 1.0121x over previous
//
#include <hip/hip_runtime.h>

// Problem constants (from reference): B=64, TOPK=2, E=16, C=1024, K=4096
#define BB    64
#define TOPK  2
#define EE    16
#define CC    1024
#define KK    4096

constexpr int RPB = 16;            // weight rows per block (4 per wave)
constexpr int P   = 16;            // max (token,slot) pairs per pass
constexpr int KS  = 8;             // K-split (partials to workspace)
constexpr int KH  = KK / KS;       // floats per K-slice (=512)
constexpr int NW  = KH / 4 / 64;   // float4 windows per slice per lane (=2)

typedef float v4f __attribute__((ext_vector_type(4)));

// ---------------------------------------------------------------------------
// Kernel 1: grid = E * 64 * KS = 8192 one-shot blocks (r7 config — best
// measured, 351.3us total).
//
// Round-9 post-mortem: occupancy lever (KS=16, ~70 VGPR, 6 waves/SIMD)
// regressed to 364us. With r7 (counted vmcnt: null) and r8 (deep burst:
// spill), all "more latency hiding" hypotheses are now rejected. This
// round is r7 byte-identical EXCEPT one A/B: weight loads are PLAIN
// (not __builtin_nontemporal_load). Hypothesis: nt bypasses L2 read-
// combining and caps the per-CU read stream (~2.5 TB/s observed) while
// the same chip sustains 6.7 TB/s on fills; the only reused input (act,
// 2 MB) fits in L2 regardless, so nt buys nothing here.
// ---------------------------------------------------------------------------
__global__ __launch_bounds__(256, 4) void moe_mlp2(
    const float* __restrict__ act, const int* __restrict__ idx,
    const float* __restrict__ W, float* __restrict__ partial)
{
    __shared__ float sact[P][KH];      // 16 x 512 x 4B = 32 KB
    __shared__ int   slist[BB * TOPK];
    __shared__ int   scnt;

    const int bid  = blockIdx.x;
    const int e    = bid >> 9;                // 512 blocks per expert
    const int ct   = (bid >> 3) & 63;         // 64 row-tiles
    const int ks   = bid & (KS - 1);          // 8 K-slices
    const int tid  = threadIdx.x;
    const int lane = tid & 63;
    const int wave = tid >> 6;
    const int row0 = ct * RPB + wave * 4;

    // --- in-block routing: both barriers happen before any heavy load ---
    if (tid == 0) scnt = 0;
    __syncthreads();
    if (tid < BB * TOPK && idx[tid] == e) {
        int pos = atomicAdd(&scnt, 1);       // LDS atomic; order irrelevant
        slist[pos] = tid;                    // pair id = b*TOPK + slot
    }
    __syncthreads();
    const int n = scnt;
    if (n == 0) return;

    const v4f* __restrict__ Wb =
        (const v4f*)(W + (size_t)(e * CC + row0) * KK + ks * KH);

    // --- async global->LDS act staging for one pass. Half-row granularity:
    //     one wave-instr = 64 lanes x 16B = 1 KB = KH/2 floats. lds dest is
    //     wave-uniform base + lane*16 (HW rule); per-lane offset lives in
    //     the global src address. ---
    auto STAGE = [&](int g, int np) {
        for (int h = wave; h < 2 * np; h += 4) {
            int pr = slist[g + (h >> 1)];
            const float* gsrc = act + (size_t)pr * KK + ks * KH
                              + (h & 1) * (KH / 2) + lane * 4;
            __builtin_amdgcn_global_load_lds(
                (const __attribute__((address_space(1))) void*)gsrc,
                (__attribute__((address_space(3))) void*)
                    &sact[h >> 1][(h & 1) * (KH / 2)],
                16, 0, 0);
        }
    };

    // --- first pass: staging FIRST (oldest), then weights (newest), then
    //     counted wait. vmcnt(8) == "everything except my 8 weight loads". ---
    v4f w[NW][4];   // kw-major: issue order == use order
    {
        const int np0 = min(P, n);
        STAGE(0, np0);
        __builtin_amdgcn_sched_barrier(0);   // pin: staging before weights
#pragma unroll
        for (int kw = 0; kw < NW; kw++)
#pragma unroll
            for (int r = 0; r < 4; r++)
                w[kw][r] = Wb[(size_t)r * (KK / 4) + kw * 64 + lane];
        __builtin_amdgcn_sched_barrier(0);   // pin: weights before wait
        asm volatile("s_waitcnt vmcnt(8)" ::: "memory");
        __builtin_amdgcn_sched_barrier(0);
        __builtin_amdgcn_s_barrier();        // all waves' staging visible
        __builtin_amdgcn_sched_barrier(0);   // no ds_read hoisted above
    }

    for (int g = 0; g < n; g += P) {
        const int np = min(P, n - g);
        if (g) {   // rare (n>16): safe full-drain restage
            __syncthreads();
            STAGE(g, np);
            __syncthreads();
        }

        // --- accumulate: val[(p<<2)|r] = lane's partial for (pair p, row r)
        float val[64];
#pragma unroll
        for (int i = 0; i < 64; i++) val[i] = 0.f;

#pragma unroll
        for (int kw = 0; kw < NW; kw++) {
            const int fb = (kw * 64 + lane) * 4;   // float idx within slice
#pragma unroll
            for (int pc = 0; pc < P / 4; pc++) {
                if (pc * 4 < np) {                  // wave-uniform guard
#pragma unroll
                    for (int j = 0; j < 4; j++) {
                        const int p = pc * 4 + j;
                        const v4f a = *(const v4f*)&sact[p][fb];
#pragma unroll
                        for (int r = 0; r < 4; r++)
                            val[(p << 2) | r] +=
                                w[kw][r].x * a.x + w[kw][r].y * a.y +
                                w[kw][r].z * a.z + w[kw][r].w * a.w;
                    }
                }
            }
        }

        // --- butterfly reduction. Invariant: after step s, slot i
        //     (i % 2^(s+1) == 0) holds the 2^(s+1)-lane partial of logical
        //     value (i | (lane & (2^(s+1)-1))). Dead pairs are exact zeros.
        if (np <= 8) {
            // 32 live slots: 5 steps within 32-lane halves (31 shfls) +
            // one cross-half add. Lanes l and l+32 both end with value l&31.
#pragma unroll
            for (int s = 0; s < 5; s++) {
                const int m = 1 << s;
                const bool hi = (lane & m) != 0;
#pragma unroll
                for (int i = 0; i < 32; i += 2 * m) {
                    float send = hi ? val[i] : val[i + m];
                    float recv = __shfl_xor(send, m, 64);
                    val[i] = (hi ? val[i + m] : val[i]) + recv;
                }
            }
            float v0 = val[0];
            v0 += __shfl_xor(v0, 32, 64);
            const int p = (lane & 31) >> 2;
            if (lane < 32 && p < np) {
                int pr = slist[g + p];
                partial[((size_t)pr * KS + ks) * CC + row0 + (lane & 3)] = v0;
            }
        } else {
            // full 64-slot butterfly: 6 steps, 63 shfls
#pragma unroll
            for (int s = 0; s < 6; s++) {
                const int m = 1 << s;
                const bool hi = (lane & m) != 0;
#pragma unroll
                for (int i = 0; i < 64; i += 2 * m) {
                    float send = hi ? val[i] : val[i + m];
                    float recv = __shfl_xor(send, m, 64);
                    val[i] = (hi ? val[i + m] : val[i]) + recv;
                }
            }
            const int p = lane >> 2;
            if (p < np) {
                int pr = slist[g + p];
                partial[((size_t)pr * KS + ks) * CC + row0 + (lane & 3)] =
                    val[0];
            }
        }
    }
}

// ---------------------------------------------------------------------------
// Kernel 2: finalize — out = resid + sum_s ew * (bias + sum_ks partial).
// 256 blocks; all reads fully coalesced; partial (4 MB) is L2/IF-hot.
// ---------------------------------------------------------------------------
__global__ __launch_bounds__(256) void finalize(
    const int* __restrict__ idx, const float* __restrict__ ew,
    const float* __restrict__ bias, const float* __restrict__ resid,
    const float* __restrict__ partial, float* __restrict__ out)
{
    const int i = blockIdx.x * 256 + threadIdx.x;   // [0, B*C)
    const int b = i >> 10;                           // C = 1024
    const int c = i & (CC - 1);
    float v = resid[i];
#pragma unroll
    for (int s = 0; s < TOPK; s++) {
        const int pr = b * TOPK + s;
        const int e  = idx[pr];
        float t = bias[e * CC + c];
#pragma unroll
        for (int ks = 0; ks < KS; ks++)
            t += partial[((size_t)pr * KS + ks) * CC + c];
        v += ew[pr] * t;
    }
    out[i] = v;
}

extern "C" void kernel_launch(void* const* d_in, const int* in_sizes, int n_in,
                              void* d_out, int out_size, void* d_ws, size_t ws_size,
                              hipStream_t stream) {
    const float* act   = (const float*)d_in[0];   // [B, TOPK, K]
    const int*   idx   = (const int*)d_in[1];     // [B, TOPK]
    const float* ew    = (const float*)d_in[2];   // [B, TOPK]
    const float* W     = (const float*)d_in[3];   // [E, C, K]
    const float* bias  = (const float*)d_in[4];   // [E, C]
    const float* resid = (const float*)d_in[5];   // [B, C]
    float* out = (float*)d_out;

    float* partial = (float*)d_ws;    // [B*TOPK][KS][C] = 4 MB

    moe_mlp2<<<EE * 64 * KS, 256, 0, stream>>>(act, idx, W, partial);
    finalize<<<(BB * CC) / 256, 256, 0, stream>>>(
        idx, ew, bias, resid, partial, out);
}

// Round 11
// 351.740 us; speedup vs baseline: 1.3885x; 1.0234x over previous
//
#include <hip/hip_runtime.h>

// Problem constants (from reference): B=64, TOPK=2, E=16, C=1024, K=4096
#define BB    64
#define TOPK  2
#define EE    16
#define CC    1024
#define KK    4096

constexpr int RPB = 16;            // weight rows per block (4 per wave)
constexpr int P   = 16;            // max (token,slot) pairs per pass
constexpr int KS  = 8;             // K-split (partials to workspace)
constexpr int KH  = KK / KS;       // floats per K-slice (=512)
constexpr int NW  = KH / 4 / 64;   // float4 windows per slice per lane (=2)

typedef float v4f __attribute__((ext_vector_type(4)));

// ---------------------------------------------------------------------------
// Kernel 1: grid = E * 64 * KS = 8192 one-shot blocks (r7 config — best
// measured, 351.3us total). FINAL REVERT: r10's nt->plain A/B regressed
// +8.7us, so nt weight loads return. All levers now measured with clean
// A/Bs from both sides of this operating point:
//   occupancy down (r1: -70), occupancy up (r4/r9: -306/-13), no-LDS
//   (r3: -47), burst depth (r8: -137 spill), vmcnt graft (r7: null),
//   cache policy (r10: -8.7). This structure is the measured argmin.
// ~220-240us of the 351us total is fixed harness cost (1 GiB re-poison
// fill at ~160us + launch gaps); the kernel portion (~110us) sits at the
// cold-HBM latency/throughput point for this access pattern.
// ---------------------------------------------------------------------------
__global__ __launch_bounds__(256, 4) void moe_mlp2(
    const float* __restrict__ act, const int* __restrict__ idx,
    const float* __restrict__ W, float* __restrict__ partial)
{
    __shared__ float sact[P][KH];      // 16 x 512 x 4B = 32 KB
    __shared__ int   slist[BB * TOPK];
    __shared__ int   scnt;

    const int bid  = blockIdx.x;
    const int e    = bid >> 9;                // 512 blocks per expert
    const int ct   = (bid >> 3) & 63;         // 64 row-tiles
    const int ks   = bid & (KS - 1);          // 8 K-slices
    const int tid  = threadIdx.x;
    const int lane = tid & 63;
    const int wave = tid >> 6;
    const int row0 = ct * RPB + wave * 4;

    // --- in-block routing: both barriers happen before any heavy load ---
    if (tid == 0) scnt = 0;
    __syncthreads();
    if (tid < BB * TOPK && idx[tid] == e) {
        int pos = atomicAdd(&scnt, 1);       // LDS atomic; order irrelevant
        slist[pos] = tid;                    // pair id = b*TOPK + slot
    }
    __syncthreads();
    const int n = scnt;
    if (n == 0) return;

    const v4f* __restrict__ Wb =
        (const v4f*)(W + (size_t)(e * CC + row0) * KK + ks * KH);

    // --- async global->LDS act staging for one pass. Half-row granularity:
    //     one wave-instr = 64 lanes x 16B = 1 KB = KH/2 floats. lds dest is
    //     wave-uniform base + lane*16 (HW rule); per-lane offset lives in
    //     the global src address. ---
    auto STAGE = [&](int g, int np) {
        for (int h = wave; h < 2 * np; h += 4) {
            int pr = slist[g + (h >> 1)];
            const float* gsrc = act + (size_t)pr * KK + ks * KH
                              + (h & 1) * (KH / 2) + lane * 4;
            __builtin_amdgcn_global_load_lds(
                (const __attribute__((address_space(1))) void*)gsrc,
                (__attribute__((address_space(3))) void*)
                    &sact[h >> 1][(h & 1) * (KH / 2)],
                16, 0, 0);
        }
    };

    // --- first pass: staging FIRST (oldest), then weights (newest), then
    //     counted wait. vmcnt(8) == "everything except my 8 weight loads". ---
    v4f w[NW][4];   // kw-major: issue order == use order
    {
        const int np0 = min(P, n);
        STAGE(0, np0);
        __builtin_amdgcn_sched_barrier(0);   // pin: staging before weights
#pragma unroll
        for (int kw = 0; kw < NW; kw++)
#pragma unroll
            for (int r = 0; r < 4; r++)
                w[kw][r] = __builtin_nontemporal_load(
                    Wb + (size_t)r * (KK / 4) + kw * 64 + lane);
        __builtin_amdgcn_sched_barrier(0);   // pin: weights before wait
        asm volatile("s_waitcnt vmcnt(8)" ::: "memory");
        __builtin_amdgcn_sched_barrier(0);
        __builtin_amdgcn_s_barrier();        // all waves' staging visible
        __builtin_amdgcn_sched_barrier(0);   // no ds_read hoisted above
    }

    for (int g = 0; g < n; g += P) {
        const int np = min(P, n - g);
        if (g) {   // rare (n>16): safe full-drain restage
            __syncthreads();
            STAGE(g, np);
            __syncthreads();
        }

        // --- accumulate: val[(p<<2)|r] = lane's partial for (pair p, row r)
        float val[64];
#pragma unroll
        for (int i = 0; i < 64; i++) val[i] = 0.f;

#pragma unroll
        for (int kw = 0; kw < NW; kw++) {
            const int fb = (kw * 64 + lane) * 4;   // float idx within slice
#pragma unroll
            for (int pc = 0; pc < P / 4; pc++) {
                if (pc * 4 < np) {                  // wave-uniform guard
#pragma unroll
                    for (int j = 0; j < 4; j++) {
                        const int p = pc * 4 + j;
                        const v4f a = *(const v4f*)&sact[p][fb];
#pragma unroll
                        for (int r = 0; r < 4; r++)
                            val[(p << 2) | r] +=
                                w[kw][r].x * a.x + w[kw][r].y * a.y +
                                w[kw][r].z * a.z + w[kw][r].w * a.w;
                    }
                }
            }
        }

        // --- butterfly reduction. Invariant: after step s, slot i
        //     (i % 2^(s+1) == 0) holds the 2^(s+1)-lane partial of logical
        //     value (i | (lane & (2^(s+1)-1))). Dead pairs are exact zeros.
        if (np <= 8) {
            // 32 live slots: 5 steps within 32-lane halves (31 shfls) +
            // one cross-half add. Lanes l and l+32 both end with value l&31.
#pragma unroll
            for (int s = 0; s < 5; s++) {
                const int m = 1 << s;
                const bool hi = (lane & m) != 0;
#pragma unroll
                for (int i = 0; i < 32; i += 2 * m) {
                    float send = hi ? val[i] : val[i + m];
                    float recv = __shfl_xor(send, m, 64);
                    val[i] = (hi ? val[i + m] : val[i]) + recv;
                }
            }
            float v0 = val[0];
            v0 += __shfl_xor(v0, 32, 64);
            const int p = (lane & 31) >> 2;
            if (lane < 32 && p < np) {
                int pr = slist[g + p];
                partial[((size_t)pr * KS + ks) * CC + row0 + (lane & 3)] = v0;
            }
        } else {
            // full 64-slot butterfly: 6 steps, 63 shfls
#pragma unroll
            for (int s = 0; s < 6; s++) {
                const int m = 1 << s;
                const bool hi = (lane & m) != 0;
#pragma unroll
                for (int i = 0; i < 64; i += 2 * m) {
                    float send = hi ? val[i] : val[i + m];
                    float recv = __shfl_xor(send, m, 64);
                    val[i] = (hi ? val[i + m] : val[i]) + recv;
                }
            }
            const int p = lane >> 2;
            if (p < np) {
                int pr = slist[g + p];
                partial[((size_t)pr * KS + ks) * CC + row0 + (lane & 3)] =
                    val[0];
            }
        }
    }
}

// ---------------------------------------------------------------------------
// Kernel 2: finalize — out = resid + sum_s ew * (bias + sum_ks partial).
// 256 blocks; all reads fully coalesced; partial (4 MB) is L2/IF-hot.
// ---------------------------------------------------------------------------
__global__ __launch_bounds__(256) void finalize(
    const int* __restrict__ idx, const float* __restrict__ ew,
    const float* __restrict__ bias, const float* __restrict__ resid,
    const float* __restrict__ partial, float* __restrict__ out)
{
    const int i = blockIdx.x * 256 + threadIdx.x;   // [0, B*C)
    const int b = i >> 10;                           // C = 1024
    const int c = i & (CC - 1);
    float v = resid[i];
#pragma unroll
    for (int s = 0; s < TOPK; s++) {
        const int pr = b * TOPK + s;
        const int e  = idx[pr];
        float t = bias[e * CC + c];
#pragma unroll
        for (int ks = 0; ks < KS; ks++)
            t += partial[((size_t)pr * KS + ks) * CC + c];
        v += ew[pr] * t;
    }
    out[i] = v;
}

extern "C" void kernel_launch(void* const* d_in, const int* in_sizes, int n_in,
                              void* d_out, int out_size, void* d_ws, size_t ws_size,
                              hipStream_t stream) {
    const float* act   = (const float*)d_in[0];   // [B, TOPK, K]
    const int*   idx   = (const int*)d_in[1];     // [B, TOPK]
    const float* ew    = (const float*)d_in[2];   // [B, TOPK]
    const float* W     = (const float*)d_in[3];   // [E, C, K]
    const float* bias  = (const float*)d_in[4];   // [E, C]
    const float* resid = (const float*)d_in[5];   // [B, C]
    float* out = (float*)d_out;

    float* partial = (float*)d_ws;    // [B*TOPK][KS][C] = 4 MB

    moe_mlp2<<<EE * 64 * KS, 256, 0, stream>>>(act, idx, W, partial);
    finalize<<<(BB * CC) / 256, 256, 0, stream>>>(
        idx, ew, bias, resid, partial, out);
}